// Round 7
// baseline (26125.568 us; speedup 1.0000x reference)
//
#include <hip/hip_runtime.h>
#include <stdint.h>

static constexpr int kB = 8, kS = 2048, kD = 1024, kF = 4096, kE = 8, kC = 512;

// ---------------- init: zero the fp32 `out` region of d_out ----------------
__global__ void init_k(uint4* __restrict__ outz) {
    const size_t n = (size_t)kB * kS * kD * 4 / 16;   // fp32 out chunk, in uint4s
    size_t stride = (size_t)gridDim.x * blockDim.x;
    for (size_t i = (size_t)blockIdx.x * blockDim.x + threadIdx.x; i < n; i += stride)
        outz[i] = (uint4){0, 0, 0, 0};
}

// ---------------- router: fp32 logits, softmax, first-wins argmax ----------------
__global__ __launch_bounds__(256) void router_k(
    const float* __restrict__ hidden, const float* __restrict__ rw,
    float* __restrict__ logits_out, int* __restrict__ expert_id, float* __restrict__ maxprob)
{
    int token = blockIdx.x * 4 + (threadIdx.x >> 6);
    int lane = threadIdx.x & 63;
    const float* hrow = hidden + (size_t)token * kD;
    float acc[8] = {0, 0, 0, 0, 0, 0, 0, 0};
    for (int d0 = lane * 4; d0 < kD; d0 += 256) {
        float4 h4 = *(const float4*)(hrow + d0);
        float hv[4] = {h4.x, h4.y, h4.z, h4.w};
        #pragma unroll
        for (int j = 0; j < 4; j++) {
            const float* wr = rw + (size_t)(d0 + j) * 8;
            float4 w0 = *(const float4*)wr, w1 = *(const float4*)(wr + 4);
            acc[0] += hv[j] * w0.x; acc[1] += hv[j] * w0.y;
            acc[2] += hv[j] * w0.z; acc[3] += hv[j] * w0.w;
            acc[4] += hv[j] * w1.x; acc[5] += hv[j] * w1.y;
            acc[6] += hv[j] * w1.z; acc[7] += hv[j] * w1.w;
        }
    }
    #pragma unroll
    for (int off = 32; off >= 1; off >>= 1) {
        #pragma unroll
        for (int e = 0; e < 8; e++) acc[e] += __shfl_down(acc[e], off, 64);
    }
    if (lane == 0) {
        float m = acc[0];
        #pragma unroll
        for (int e = 1; e < 8; e++) m = fmaxf(m, acc[e]);
        float ex[8], s = 0.f;
        #pragma unroll
        for (int e = 0; e < 8; e++) { ex[e] = expf(acc[e] - m); s += ex[e]; }
        int best = 0; float bv = -1.f;
        #pragma unroll
        for (int e = 0; e < 8; e++) {
            float p = ex[e] / s;
            if (p > bv) { bv = p; best = e; }    // strict > : first max wins = np.argmax
            logits_out[(size_t)token * 8 + e] = acc[e];   // fp32 store
        }
        expert_id[token] = best;
        maxprob[token] = bv;
    }
}

// ---------------- capacity scan ----------------
__global__ __launch_bounds__(64) void scan_k(
    const int* __restrict__ expert_id, int* __restrict__ slot_token,
    int* __restrict__ counts, float* __restrict__ expidx_out)
{
    __shared__ int eids[kS];
    int b = blockIdx.x, tid = threadIdx.x;
    for (int s = tid; s < kS; s += 64) eids[s] = expert_id[b * kS + s];
    __syncthreads();
    if (tid < kE) {
        int e = tid, cnt = 0;
        for (int s = 0; s < kS; s++) {
            if (eids[s] == e) {
                if (cnt < kC) {
                    slot_token[(b * kE + e) * kC + cnt] = s;
                    expidx_out[b * kS + s] = (float)e;
                    cnt++;
                } else {
                    expidx_out[b * kS + s] = 0.f;  // dropped -> argmax(zeros)=0
                }
            }
        }
        counts[b * kE + e] = cnt;
        for (int c = cnt; c < kC; c++) slot_token[(b * kE + e) * kC + c] = -1;
    }
}

// ---------------- naive fp32 GEMM1: H[c][f] = relu(sum_d A[c][d] * wi[e][d][f]) ----------------
__global__ __launch_bounds__(256) void ngemm1_k(
    const float* __restrict__ hidden, const float* __restrict__ wi,
    const int* __restrict__ slot_token, const int* __restrict__ counts,
    float* __restrict__ H, int pair)
{
    int b = pair >> 3, e = pair & 7;
    int cnt = counts[pair];
    int c0 = blockIdx.y * 64, f0 = blockIdx.x * 64;
    if (c0 >= cnt) return;

    __shared__ float As[64][17];
    __shared__ float Bs[16][65];
    __shared__ int slots[64];
    int tx = threadIdx.x, ty = threadIdx.y;
    int tid = ty * 16 + tx;
    if (tid < 64) slots[tid] = slot_token[pair * kC + c0 + tid];
    __syncthreads();

    float acc[4][4];
    #pragma unroll
    for (int i = 0; i < 4; i++)
        #pragma unroll
        for (int j = 0; j < 4; j++) acc[i][j] = 0.f;

    int ar = tid >> 2, ak = (tid & 3) * 4;
    int bd = tid >> 4, bf = (tid & 15) * 4;
    const float* wie = wi + (size_t)e * kD * kF;

    for (int k0 = 0; k0 < kD; k0 += 16) {
        int sl = slots[ar];
        if (sl >= 0) {
            float4 v = *(const float4*)(hidden + (size_t)(b * kS + sl) * kD + k0 + ak);
            As[ar][ak] = v.x; As[ar][ak + 1] = v.y; As[ar][ak + 2] = v.z; As[ar][ak + 3] = v.w;
        } else {
            As[ar][ak] = 0.f; As[ar][ak + 1] = 0.f; As[ar][ak + 2] = 0.f; As[ar][ak + 3] = 0.f;
        }
        float4 w = *(const float4*)(wie + (size_t)(k0 + bd) * kF + f0 + bf);
        Bs[bd][bf] = w.x; Bs[bd][bf + 1] = w.y; Bs[bd][bf + 2] = w.z; Bs[bd][bf + 3] = w.w;
        __syncthreads();
        #pragma unroll
        for (int kk = 0; kk < 16; kk++) {
            float a[4], bv[4];
            #pragma unroll
            for (int i = 0; i < 4; i++) a[i] = As[ty * 4 + i][kk];
            #pragma unroll
            for (int j = 0; j < 4; j++) bv[j] = Bs[kk][tx * 4 + j];
            #pragma unroll
            for (int i = 0; i < 4; i++)
                #pragma unroll
                for (int j = 0; j < 4; j++) acc[i][j] += a[i] * bv[j];
        }
        __syncthreads();
    }

    #pragma unroll
    for (int i = 0; i < 4; i++) {
        int row = c0 + ty * 4 + i;
        #pragma unroll
        for (int j = 0; j < 4; j++)
            H[(size_t)row * kF + f0 + tx * 4 + j] = fmaxf(acc[i][j], 0.f);
    }
}

// ---------------- naive fp32 GEMM2: out[s][d] = (sum_f H[c][f] * wo[e][f][d]) * p ----------------
__global__ __launch_bounds__(256) void ngemm2_k(
    const float* __restrict__ H, const float* __restrict__ wo,
    const int* __restrict__ slot_token, const int* __restrict__ counts,
    const float* __restrict__ maxprob, float* __restrict__ outp, int pair)
{
    int b = pair >> 3, e = pair & 7;
    int cnt = counts[pair];
    int c0 = blockIdx.y * 64, d0 = blockIdx.x * 64;
    if (c0 >= cnt) return;

    __shared__ float As[64][17];
    __shared__ float Bs[16][65];
    __shared__ int slots[64];
    int tx = threadIdx.x, ty = threadIdx.y;
    int tid = ty * 16 + tx;
    if (tid < 64) slots[tid] = slot_token[pair * kC + c0 + tid];
    __syncthreads();

    float acc[4][4];
    #pragma unroll
    for (int i = 0; i < 4; i++)
        #pragma unroll
        for (int j = 0; j < 4; j++) acc[i][j] = 0.f;

    int ar = tid >> 2, ak = (tid & 3) * 4;
    int bd = tid >> 4, bf = (tid & 15) * 4;
    const float* woe = wo + (size_t)e * kF * kD;

    for (int k0 = 0; k0 < kF; k0 += 16) {
        float4 v = *(const float4*)(H + (size_t)(c0 + ar) * kF + k0 + ak);
        As[ar][ak] = v.x; As[ar][ak + 1] = v.y; As[ar][ak + 2] = v.z; As[ar][ak + 3] = v.w;
        float4 w = *(const float4*)(woe + (size_t)(k0 + bd) * kD + d0 + bf);
        Bs[bd][bf] = w.x; Bs[bd][bf + 1] = w.y; Bs[bd][bf + 2] = w.z; Bs[bd][bf + 3] = w.w;
        __syncthreads();
        #pragma unroll
        for (int kk = 0; kk < 16; kk++) {
            float a[4], bv[4];
            #pragma unroll
            for (int i = 0; i < 4; i++) a[i] = As[ty * 4 + i][kk];
            #pragma unroll
            for (int j = 0; j < 4; j++) bv[j] = Bs[kk][tx * 4 + j];
            #pragma unroll
            for (int i = 0; i < 4; i++)
                #pragma unroll
                for (int j = 0; j < 4; j++) acc[i][j] += a[i] * bv[j];
        }
        __syncthreads();
    }

    #pragma unroll
    for (int i = 0; i < 4; i++) {
        int s = slots[ty * 4 + i];
        if (s >= 0) {
            float p = maxprob[b * kS + s];
            size_t ob = (size_t)(b * kS + s) * kD;
            #pragma unroll
            for (int j = 0; j < 4; j++)
                outp[ob + d0 + tx * 4 + j] = acc[i][j] * p;   // fp32 store
        }
    }
}

extern "C" void kernel_launch(void* const* d_in, const int* in_sizes, int n_in,
                              void* d_out, int out_size, void* d_ws, size_t ws_size,
                              hipStream_t stream)
{
    const float* hidden = (const float*)d_in[0];
    const float* rw     = (const float*)d_in[1];
    const float* wi     = (const float*)d_in[2];
    const float* wo     = (const float*)d_in[3];
    // d_out is FLOAT32 (reference output dtype): [out | router_logits | expert_index]
    float* outp   = (float*)d_out;
    float* logits = outp + (size_t)kB * kS * kD;
    float* expidx = logits + (size_t)kB * kS * kE;

    char* ws = (char*)d_ws;
    size_t off = 0;
    auto alloc = [&](size_t bytes) -> char* {
        char* p = ws + off; off += (bytes + 255) & ~(size_t)255; return p;
    };
    int*   slot_token = (int*)  alloc((size_t)kB * kE * kC * 4);
    int*   counts     = (int*)  alloc((size_t)kB * kE * 4);
    int*   expert_id  = (int*)  alloc((size_t)kB * kS * 4);
    float* maxprob    = (float*)alloc((size_t)kB * kS * 4);
    float* H          = (float*)alloc((size_t)kC * kF * 4);   // 8 MiB, one pair at a time
    // total footprint: ~8.6 MiB

    init_k<<<2048, 256, 0, stream>>>((uint4*)outp);
    router_k<<<kB * kS / 4, 256, 0, stream>>>(hidden, rw, logits, expert_id, maxprob);
    scan_k<<<kB, 64, 0, stream>>>(expert_id, slot_token, counts, expidx);

    for (int pair = 0; pair < kB * kE; pair++) {
        ngemm1_k<<<dim3(kF / 64, kC / 64), dim3(16, 16), 0, stream>>>(
            hidden, wi, slot_token, counts, H, pair);
        ngemm2_k<<<dim3(kD / 64, kC / 64), dim3(16, 16), 0, stream>>>(
            H, wo, slot_token, counts, maxprob, outp, pair);
    }
}

// Round 8
// 1090.204 us; speedup vs baseline: 23.9639x; 23.9639x over previous
//
#include <hip/hip_runtime.h>
#include <stdint.h>

static constexpr int kB = 8, kS = 2048, kD = 1024, kF = 4096, kE = 8, kC = 512;

typedef unsigned short u16;
typedef __attribute__((ext_vector_type(8))) short bf16x8;
typedef __attribute__((ext_vector_type(4))) float f32x4;

__device__ __forceinline__ u16 f2bf(float f) {
    union { float f; uint32_t u; } v; v.f = f;
    return (u16)((v.u + 0x7fffu + ((v.u >> 16) & 1u)) >> 16);
}
__device__ __forceinline__ void gload16(const u16* g, u16* l) {
    __builtin_amdgcn_global_load_lds(
        (__attribute__((address_space(1))) void*)(u16*)g,
        (__attribute__((address_space(3))) void*)l, 16, 0, 0);
}

// ---------------- init: zero the fp32 `out` region of d_out ----------------
__global__ void init_k(uint4* __restrict__ outz) {
    const size_t n = (size_t)kB * kS * kD * 4 / 16;
    size_t stride = (size_t)gridDim.x * blockDim.x;
    for (size_t i = (size_t)blockIdx.x * blockDim.x + threadIdx.x; i < n; i += stride)
        outz[i] = (uint4){0, 0, 0, 0};
}

// ---------------- router: fp32 logits, softmax, first-wins argmax (round-7 proven) ----------
__global__ __launch_bounds__(256) void router_k(
    const float* __restrict__ hidden, const float* __restrict__ rw,
    float* __restrict__ logits_out, int* __restrict__ expert_id, float* __restrict__ maxprob)
{
    int token = blockIdx.x * 4 + (threadIdx.x >> 6);
    int lane = threadIdx.x & 63;
    const float* hrow = hidden + (size_t)token * kD;
    float acc[8] = {0, 0, 0, 0, 0, 0, 0, 0};
    for (int d0 = lane * 4; d0 < kD; d0 += 256) {
        float4 h4 = *(const float4*)(hrow + d0);
        float hv[4] = {h4.x, h4.y, h4.z, h4.w};
        #pragma unroll
        for (int j = 0; j < 4; j++) {
            const float* wr = rw + (size_t)(d0 + j) * 8;
            float4 w0 = *(const float4*)wr, w1 = *(const float4*)(wr + 4);
            acc[0] += hv[j] * w0.x; acc[1] += hv[j] * w0.y;
            acc[2] += hv[j] * w0.z; acc[3] += hv[j] * w0.w;
            acc[4] += hv[j] * w1.x; acc[5] += hv[j] * w1.y;
            acc[6] += hv[j] * w1.z; acc[7] += hv[j] * w1.w;
        }
    }
    #pragma unroll
    for (int off = 32; off >= 1; off >>= 1) {
        #pragma unroll
        for (int e = 0; e < 8; e++) acc[e] += __shfl_down(acc[e], off, 64);
    }
    if (lane == 0) {
        float m = acc[0];
        #pragma unroll
        for (int e = 1; e < 8; e++) m = fmaxf(m, acc[e]);
        float ex[8], s = 0.f;
        #pragma unroll
        for (int e = 0; e < 8; e++) { ex[e] = expf(acc[e] - m); s += ex[e]; }
        int best = 0; float bv = -1.f;
        #pragma unroll
        for (int e = 0; e < 8; e++) {
            float p = ex[e] / s;
            if (p > bv) { bv = p; best = e; }
            logits_out[(size_t)token * 8 + e] = acc[e];
        }
        expert_id[token] = best;
        maxprob[token] = bv;
    }
}

// ---------------- capacity scan (round-7 proven) ----------------
__global__ __launch_bounds__(64) void scan_k(
    const int* __restrict__ expert_id, int* __restrict__ slot_token,
    int* __restrict__ counts, float* __restrict__ expidx_out)
{
    __shared__ int eids[kS];
    int b = blockIdx.x, tid = threadIdx.x;
    for (int s = tid; s < kS; s += 64) eids[s] = expert_id[b * kS + s];
    __syncthreads();
    if (tid < kE) {
        int e = tid, cnt = 0;
        for (int s = 0; s < kS; s++) {
            if (eids[s] == e) {
                if (cnt < kC) {
                    slot_token[(b * kE + e) * kC + cnt] = s;
                    expidx_out[b * kS + s] = (float)e;
                    cnt++;
                } else {
                    expidx_out[b * kS + s] = 0.f;
                }
            }
        }
        counts[b * kE + e] = cnt;
        for (int c = cnt; c < kC; c++) slot_token[(b * kE + e) * kC + c] = -1;
    }
}

// ---------------- transpose fp32 [R][Cn] -> bf16 [Cn][R]; blockIdx.z = expert ----------------
__global__ void transpose_k(const float* __restrict__ src, u16* __restrict__ dst, int R, int Cn) {
    __shared__ u16 t[32][33];
    size_t eo = (size_t)blockIdx.z * R * Cn;
    int c0 = blockIdx.x * 32, r0 = blockIdx.y * 32;
    int tx = threadIdx.x, ty = threadIdx.y;
    #pragma unroll
    for (int i = 0; i < 4; i++)
        t[ty + i * 8][tx] = f2bf(src[eo + (size_t)(r0 + ty + i * 8) * Cn + c0 + tx]);
    __syncthreads();
    #pragma unroll
    for (int i = 0; i < 4; i++)
        dst[eo + (size_t)(c0 + ty + i * 8) * R + r0 + tx] = t[tx][ty + i * 8];
}

// ---------------- MFMA GEMM1: H = relu(gather(hidden) @ wi), bf16 H ----------------
// pair = pair0 + blockIdx.y * pstride; weights at wiT + (pair&7)*wstride
__global__ __launch_bounds__(256) void gemm1_k(
    const float* __restrict__ hidden, const u16* __restrict__ wiT, size_t wstride,
    const int* __restrict__ slot_token, const int* __restrict__ counts,
    u16* __restrict__ Hbuf, int pair0, int pstride)
{
    int pl = blockIdx.y;
    int pair = pair0 + pl * pstride;
    int b = pair >> 3, e = pair & 7;
    const u16* wbase = wiT + (size_t)e * wstride;
    constexpr int NT = kF / 128;  // 32
    int mt = blockIdx.x / NT, nt = blockIdx.x % NT;
    int cnt = counts[pair];
    if (mt * 128 >= cnt) return;

    __shared__ __align__(16) u16 As[128 * 32];
    __shared__ __align__(16) u16 Bs[128 * 32];
    __shared__ int slots[128];
    int tid = threadIdx.x, wave = tid >> 6, lane = tid & 63;
    if (tid < 128) slots[tid] = slot_token[pair * kC + mt * 128 + tid];
    __syncthreads();

    int wr = wave >> 1, wc = wave & 1;
    int fr = lane & 15, fq = lane >> 4;
    int srow = lane >> 2, kb = (lane & 3) * 8;
    int arow = tid >> 1, aks = (tid & 1) * 16;   // A staging: 1 thread = 16 elems
    int asl = slots[arow];
    const float* asrc = (asl >= 0) ? hidden + (size_t)(b * kS + asl) * kD + aks : nullptr;

    f32x4 acc[4][4];
    #pragma unroll
    for (int m = 0; m < 4; m++)
        #pragma unroll
        for (int n = 0; n < 4; n++) acc[m][n] = (f32x4){0.f, 0.f, 0.f, 0.f};

    for (int k0 = 0; k0 < kD; k0 += 32) {
        u16 o[16];
        if (asl >= 0) {
            const float4* s4 = (const float4*)(asrc + k0);
            float4 v0 = s4[0], v1 = s4[1], v2 = s4[2], v3 = s4[3];
            o[0] = f2bf(v0.x);  o[1] = f2bf(v0.y);  o[2] = f2bf(v0.z);  o[3] = f2bf(v0.w);
            o[4] = f2bf(v1.x);  o[5] = f2bf(v1.y);  o[6] = f2bf(v1.z);  o[7] = f2bf(v1.w);
            o[8] = f2bf(v2.x);  o[9] = f2bf(v2.y);  o[10] = f2bf(v2.z); o[11] = f2bf(v2.w);
            o[12] = f2bf(v3.x); o[13] = f2bf(v3.y); o[14] = f2bf(v3.z); o[15] = f2bf(v3.w);
        } else {
            #pragma unroll
            for (int i = 0; i < 16; i++) o[i] = 0;
        }
        *(uint4*)(As + arow * 32 + aks)     = ((const uint4*)o)[0];
        *(uint4*)(As + arow * 32 + aks + 8) = ((const uint4*)o)[1];
        #pragma unroll
        for (int i = 0; i < 2; i++) {
            int seg = wave + i * 4;
            int row = seg * 16 + srow;
            const u16* srcB = wbase + ((size_t)(nt * 128 + row)) * kD + k0 + kb;
            gload16(srcB, Bs + seg * 512);
        }
        __syncthreads();
        bf16x8 af[4], bfr[4];
        #pragma unroll
        for (int m = 0; m < 4; m++)
            af[m] = *(const bf16x8*)(As + (wr * 64 + m * 16 + fr) * 32 + fq * 8);
        #pragma unroll
        for (int n = 0; n < 4; n++)
            bfr[n] = *(const bf16x8*)(Bs + (wc * 64 + n * 16 + fr) * 32 + fq * 8);
        #pragma unroll
        for (int m = 0; m < 4; m++)
            #pragma unroll
            for (int n = 0; n < 4; n++)
                acc[m][n] = __builtin_amdgcn_mfma_f32_16x16x32_bf16(af[m], bfr[n], acc[m][n], 0, 0, 0);
        __syncthreads();
    }

    size_t hbase = (size_t)pl * kC * kF;
    int r0 = mt * 128 + wr * 64, c0 = nt * 128 + wc * 64;
    #pragma unroll
    for (int m = 0; m < 4; m++) {
        #pragma unroll
        for (int j = 0; j < 4; j++) {
            int row = r0 + m * 16 + fq * 4 + j;
            size_t rb = hbase + (size_t)row * kF;
            #pragma unroll
            for (int n = 0; n < 4; n++) {
                int col = c0 + n * 16 + fr;
                Hbuf[rb + col] = f2bf(fmaxf(acc[m][n][j], 0.f));
            }
        }
    }
}

// ---------------- MFMA GEMM2: out = (H @ wo) * max_prob, fp32 scatter ----------------
__global__ __launch_bounds__(256) void gemm2_k(
    const u16* __restrict__ Hbuf, const u16* __restrict__ woT, size_t wstride,
    const int* __restrict__ slot_token, const int* __restrict__ counts,
    const float* __restrict__ maxprob, float* __restrict__ outp, int pair0, int pstride)
{
    int pl = blockIdx.y;
    int pair = pair0 + pl * pstride;
    int b = pair >> 3, e = pair & 7;
    const u16* wbase = woT + (size_t)e * wstride;
    constexpr int NT = kD / 128;  // 8
    int mt = blockIdx.x / NT, nt = blockIdx.x % NT;
    int cnt = counts[pair];
    if (mt * 128 >= cnt) return;

    __shared__ __align__(16) u16 As[128 * 32];
    __shared__ __align__(16) u16 Bs[128 * 32];
    __shared__ int slots[128];
    int tid = threadIdx.x, wave = tid >> 6, lane = tid & 63;
    if (tid < 128) slots[tid] = slot_token[pair * kC + mt * 128 + tid];
    __syncthreads();

    int wr = wave >> 1, wc = wave & 1;
    int fr = lane & 15, fq = lane >> 4;
    int srow = lane >> 2, kb = (lane & 3) * 8;
    f32x4 acc[4][4];
    #pragma unroll
    for (int m = 0; m < 4; m++)
        #pragma unroll
        for (int n = 0; n < 4; n++) acc[m][n] = (f32x4){0.f, 0.f, 0.f, 0.f};

    for (int k0 = 0; k0 < kF; k0 += 32) {
        #pragma unroll
        for (int i = 0; i < 2; i++) {
            int seg = wave + i * 4;
            int row = seg * 16 + srow;
            const u16* srcA = Hbuf + ((size_t)pl * kC + mt * 128 + row) * kF + k0 + kb;
            gload16(srcA, As + seg * 512);
            const u16* srcB = wbase + ((size_t)(nt * 128 + row)) * kF + k0 + kb;
            gload16(srcB, Bs + seg * 512);
        }
        __syncthreads();
        bf16x8 af[4], bfr[4];
        #pragma unroll
        for (int m = 0; m < 4; m++)
            af[m] = *(const bf16x8*)(As + (wr * 64 + m * 16 + fr) * 32 + fq * 8);
        #pragma unroll
        for (int n = 0; n < 4; n++)
            bfr[n] = *(const bf16x8*)(Bs + (wc * 64 + n * 16 + fr) * 32 + fq * 8);
        #pragma unroll
        for (int m = 0; m < 4; m++)
            #pragma unroll
            for (int n = 0; n < 4; n++)
                acc[m][n] = __builtin_amdgcn_mfma_f32_16x16x32_bf16(af[m], bfr[n], acc[m][n], 0, 0, 0);
        __syncthreads();
    }

    int c0 = nt * 128 + wc * 64;
    #pragma unroll
    for (int m = 0; m < 4; m++) {
        #pragma unroll
        for (int j = 0; j < 4; j++) {
            int rlocal = wr * 64 + m * 16 + fq * 4 + j;
            int s = slots[rlocal];
            if (s >= 0) {
                float p = maxprob[b * kS + s];
                size_t ob = (size_t)(b * kS + s) * kD;
                #pragma unroll
                for (int n = 0; n < 4; n++) {
                    int col = c0 + n * 16 + fr;
                    outp[ob + col] = acc[m][n][j] * p;  // fp32 store
                }
            }
        }
    }
}

// ---------------- naive fp32 fallback (round-7 proven) ----------------
__global__ __launch_bounds__(256) void ngemm1_k(
    const float* __restrict__ hidden, const float* __restrict__ wi,
    const int* __restrict__ slot_token, const int* __restrict__ counts,
    float* __restrict__ H, int pair)
{
    int b = pair >> 3, e = pair & 7;
    int cnt = counts[pair];
    int c0 = blockIdx.y * 64, f0 = blockIdx.x * 64;
    if (c0 >= cnt) return;
    __shared__ float As[64][17];
    __shared__ float Bs[16][65];
    __shared__ int slots[64];
    int tx = threadIdx.x, ty = threadIdx.y;
    int tid = ty * 16 + tx;
    if (tid < 64) slots[tid] = slot_token[pair * kC + c0 + tid];
    __syncthreads();
    float acc[4][4];
    #pragma unroll
    for (int i = 0; i < 4; i++)
        #pragma unroll
        for (int j = 0; j < 4; j++) acc[i][j] = 0.f;
    int ar = tid >> 2, ak = (tid & 3) * 4;
    int bd = tid >> 4, bf = (tid & 15) * 4;
    const float* wie = wi + (size_t)e * kD * kF;
    for (int k0 = 0; k0 < kD; k0 += 16) {
        int sl = slots[ar];
        if (sl >= 0) {
            float4 v = *(const float4*)(hidden + (size_t)(b * kS + sl) * kD + k0 + ak);
            As[ar][ak] = v.x; As[ar][ak + 1] = v.y; As[ar][ak + 2] = v.z; As[ar][ak + 3] = v.w;
        } else {
            As[ar][ak] = 0.f; As[ar][ak + 1] = 0.f; As[ar][ak + 2] = 0.f; As[ar][ak + 3] = 0.f;
        }
        float4 w = *(const float4*)(wie + (size_t)(k0 + bd) * kF + f0 + bf);
        Bs[bd][bf] = w.x; Bs[bd][bf + 1] = w.y; Bs[bd][bf + 2] = w.z; Bs[bd][bf + 3] = w.w;
        __syncthreads();
        #pragma unroll
        for (int kk = 0; kk < 16; kk++) {
            float a[4], bv[4];
            #pragma unroll
            for (int i = 0; i < 4; i++) a[i] = As[ty * 4 + i][kk];
            #pragma unroll
            for (int j = 0; j < 4; j++) bv[j] = Bs[kk][tx * 4 + j];
            #pragma unroll
            for (int i = 0; i < 4; i++)
                #pragma unroll
                for (int j = 0; j < 4; j++) acc[i][j] += a[i] * bv[j];
        }
        __syncthreads();
    }
    #pragma unroll
    for (int i = 0; i < 4; i++) {
        int row = c0 + ty * 4 + i;
        #pragma unroll
        for (int j = 0; j < 4; j++)
            H[(size_t)row * kF + f0 + tx * 4 + j] = fmaxf(acc[i][j], 0.f);
    }
}

__global__ __launch_bounds__(256) void ngemm2_k(
    const float* __restrict__ H, const float* __restrict__ wo,
    const int* __restrict__ slot_token, const int* __restrict__ counts,
    const float* __restrict__ maxprob, float* __restrict__ outp, int pair)
{
    int b = pair >> 3, e = pair & 7;
    int cnt = counts[pair];
    int c0 = blockIdx.y * 64, d0 = blockIdx.x * 64;
    if (c0 >= cnt) return;
    __shared__ float As[64][17];
    __shared__ float Bs[16][65];
    __shared__ int slots[64];
    int tx = threadIdx.x, ty = threadIdx.y;
    int tid = ty * 16 + tx;
    if (tid < 64) slots[tid] = slot_token[pair * kC + c0 + tid];
    __syncthreads();
    float acc[4][4];
    #pragma unroll
    for (int i = 0; i < 4; i++)
        #pragma unroll
        for (int j = 0; j < 4; j++) acc[i][j] = 0.f;
    int ar = tid >> 2, ak = (tid & 3) * 4;
    int bd = tid >> 4, bf = (tid & 15) * 4;
    const float* woe = wo + (size_t)e * kF * kD;
    for (int k0 = 0; k0 < kF; k0 += 16) {
        float4 v = *(const float4*)(H + (size_t)(c0 + ar) * kF + k0 + ak);
        As[ar][ak] = v.x; As[ar][ak + 1] = v.y; As[ar][ak + 2] = v.z; As[ar][ak + 3] = v.w;
        float4 w = *(const float4*)(woe + (size_t)(k0 + bd) * kD + d0 + bf);
        Bs[bd][bf] = w.x; Bs[bd][bf + 1] = w.y; Bs[bd][bf + 2] = w.z; Bs[bd][bf + 3] = w.w;
        __syncthreads();
        #pragma unroll
        for (int kk = 0; kk < 16; kk++) {
            float a[4], bv[4];
            #pragma unroll
            for (int i = 0; i < 4; i++) a[i] = As[ty * 4 + i][kk];
            #pragma unroll
            for (int j = 0; j < 4; j++) bv[j] = Bs[kk][tx * 4 + j];
            #pragma unroll
            for (int i = 0; i < 4; i++)
                #pragma unroll
                for (int j = 0; j < 4; j++) acc[i][j] += a[i] * bv[j];
        }
        __syncthreads();
    }
    #pragma unroll
    for (int i = 0; i < 4; i++) {
        int s = slots[ty * 4 + i];
        if (s >= 0) {
            float p = maxprob[b * kS + s];
            size_t ob = (size_t)(b * kS + s) * kD;
            #pragma unroll
            for (int j = 0; j < 4; j++)
                outp[ob + d0 + tx * 4 + j] = acc[i][j] * p;
        }
    }
}

extern "C" void kernel_launch(void* const* d_in, const int* in_sizes, int n_in,
                              void* d_out, int out_size, void* d_ws, size_t ws_size,
                              hipStream_t stream)
{
    const float* hidden = (const float*)d_in[0];
    const float* rw     = (const float*)d_in[1];
    const float* wi     = (const float*)d_in[2];
    const float* wo     = (const float*)d_in[3];
    float* outp   = (float*)d_out;
    float* logits = outp + (size_t)kB * kS * kD;
    float* expidx = logits + (size_t)kB * kS * kE;

    char* ws = (char*)d_ws;
    size_t off = 0;
    auto alloc = [&](size_t bytes) -> char* {
        char* p = ws + off; off += (bytes + 255) & ~(size_t)255; return p;
    };
    int*   slot_token = (int*)  alloc((size_t)kB * kE * kC * 4);
    int*   counts     = (int*)  alloc((size_t)kB * kE * 4);
    int*   expert_id  = (int*)  alloc((size_t)kB * kS * 4);
    float* maxprob    = (float*)alloc((size_t)kB * kS * 4);
    size_t small_off = off;               // ~1.2 MiB

    const size_t wsz = (size_t)kD * kF * 2;       // 8 MiB per expert, bf16
    const size_t hsz = (size_t)kC * kF * 2;       // 4 MiB per pair, bf16

    init_k<<<2048, 256, 0, stream>>>((uint4*)outp);
    router_k<<<kB * kS / 4, 256, 0, stream>>>(hidden, rw, logits, expert_id, maxprob);
    scan_k<<<kB, 64, 0, stream>>>(expert_id, slot_token, counts, expidx);

    if (ws_size >= small_off + 2 * kE * wsz + 4 * hsz) {
        // ---- tier A: all-expert transposed weights, big fused pair groups ----
        u16* wiT = (u16*)alloc(kE * wsz);   // 64 MiB
        u16* woT = (u16*)alloc(kE * wsz);   // 64 MiB
        int Gb = (int)((ws_size - off) / hsz);
        if (Gb > kB * kE) Gb = kB * kE;
        u16* Hbuf = (u16*)alloc((size_t)Gb * hsz);
        transpose_k<<<dim3(kF / 32, kD / 32, kE), dim3(32, 8), 0, stream>>>(wi, wiT, kD, kF);
        transpose_k<<<dim3(kD / 32, kF / 32, kE), dim3(32, 8), 0, stream>>>(wo, woT, kF, kD);
        for (int p0 = 0; p0 < kB * kE; p0 += Gb) {
            int g = kB * kE - p0 < Gb ? kB * kE - p0 : Gb;
            gemm1_k<<<dim3((kC / 128) * (kF / 128), g), 256, 0, stream>>>(
                hidden, wiT, (size_t)kD * kF, slot_token, counts, Hbuf, p0, 1);
            gemm2_k<<<dim3((kC / 128) * (kD / 128), g), 256, 0, stream>>>(
                Hbuf, woT, (size_t)kD * kF, slot_token, counts, maxprob, outp, p0, 1);
        }
    } else if (ws_size >= small_off + 2 * wsz + hsz) {
        // ---- tier B: per-expert transposed weights ----
        u16* wiT = (u16*)alloc(wsz);
        u16* woT = (u16*)alloc(wsz);
        int Gb = (int)((ws_size - off) / hsz);
        if (Gb > kB) Gb = kB;
        u16* Hbuf = (u16*)alloc((size_t)Gb * hsz);
        for (int e = 0; e < kE; e++) {
            transpose_k<<<dim3(kF / 32, kD / 32, 1), dim3(32, 8), 0, stream>>>(
                wi + (size_t)e * kD * kF, wiT, kD, kF);
            transpose_k<<<dim3(kD / 32, kF / 32, 1), dim3(32, 8), 0, stream>>>(
                wo + (size_t)e * kD * kF, woT, kF, kD);
            for (int b0 = 0; b0 < kB; b0 += Gb) {
                int g = kB - b0 < Gb ? kB - b0 : Gb;
                gemm1_k<<<dim3((kC / 128) * (kF / 128), g), 256, 0, stream>>>(
                    hidden, wiT, 0, slot_token, counts, Hbuf, b0 * kE + e, kE);
                gemm2_k<<<dim3((kC / 128) * (kD / 128), g), 256, 0, stream>>>(
                    Hbuf, woT, 0, slot_token, counts, maxprob, outp, b0 * kE + e, kE);
            }
        }
    } else {
        // ---- tier C: proven naive fp32 fallback ----
        float* H = (float*)alloc((size_t)kC * kF * 4);
        for (int pair = 0; pair < kB * kE; pair++) {
            ngemm1_k<<<dim3(kF / 64, kC / 64), dim3(16, 16), 0, stream>>>(
                hidden, wi, slot_token, counts, H, pair);
            ngemm2_k<<<dim3(kD / 64, kC / 64), dim3(16, 16), 0, stream>>>(
                H, wo, slot_token, counts, maxprob, outp, pair);
        }
    }
}

// Round 9
// 951.592 us; speedup vs baseline: 27.4546x; 1.1457x over previous
//
#include <hip/hip_runtime.h>
#include <stdint.h>

static constexpr int kB = 8, kS = 2048, kD = 1024, kF = 4096, kE = 8, kC = 512;

typedef unsigned short u16;
typedef __attribute__((ext_vector_type(8))) short bf16x8;
typedef __attribute__((ext_vector_type(4))) float f32x4;

__device__ __forceinline__ u16 f2bf(float f) {
    union { float f; uint32_t u; } v; v.f = f;
    return (u16)((v.u + 0x7fffu + ((v.u >> 16) & 1u)) >> 16);
}
__device__ __forceinline__ void gload16(const u16* g, u16* l) {
    __builtin_amdgcn_global_load_lds(
        (__attribute__((address_space(1))) void*)(u16*)g,
        (__attribute__((address_space(3))) void*)l, 16, 0, 0);
}

// ---------------- init: zero the fp32 `out` region of d_out ----------------
__global__ void init_k(uint4* __restrict__ outz) {
    const size_t n = (size_t)kB * kS * kD * 4 / 16;
    size_t stride = (size_t)gridDim.x * blockDim.x;
    for (size_t i = (size_t)blockIdx.x * blockDim.x + threadIdx.x; i < n; i += stride)
        outz[i] = (uint4){0, 0, 0, 0};
}

// ---------------- hidden fp32 -> bf16 image; block 0 also zeroes the zero page ----------------
__global__ void conv_hidden_k(const float* __restrict__ src, u16* __restrict__ hbf,
                              uint4* __restrict__ zerobuf) {
    if (blockIdx.x == 0 && threadIdx.x < 144) zerobuf[threadIdx.x] = (uint4){0, 0, 0, 0};
    const size_t n = (size_t)kB * kS * kD;
    size_t i0 = ((size_t)blockIdx.x * blockDim.x + threadIdx.x) * 8;
    size_t stride = (size_t)gridDim.x * blockDim.x * 8;
    for (size_t i = i0; i < n; i += stride) {
        float4 a = *(const float4*)(src + i);
        float4 b = *(const float4*)(src + i + 4);
        u16 t[8] = {f2bf(a.x), f2bf(a.y), f2bf(a.z), f2bf(a.w),
                    f2bf(b.x), f2bf(b.y), f2bf(b.z), f2bf(b.w)};
        *(uint4*)(hbf + i) = *(const uint4*)t;
    }
}

// ---------------- router: fp32 logits, softmax, first-wins argmax (proven) ----------
__global__ __launch_bounds__(256) void router_k(
    const float* __restrict__ hidden, const float* __restrict__ rw,
    float* __restrict__ logits_out, int* __restrict__ expert_id, float* __restrict__ maxprob)
{
    int token = blockIdx.x * 4 + (threadIdx.x >> 6);
    int lane = threadIdx.x & 63;
    const float* hrow = hidden + (size_t)token * kD;
    float acc[8] = {0, 0, 0, 0, 0, 0, 0, 0};
    for (int d0 = lane * 4; d0 < kD; d0 += 256) {
        float4 h4 = *(const float4*)(hrow + d0);
        float hv[4] = {h4.x, h4.y, h4.z, h4.w};
        #pragma unroll
        for (int j = 0; j < 4; j++) {
            const float* wr = rw + (size_t)(d0 + j) * 8;
            float4 w0 = *(const float4*)wr, w1 = *(const float4*)(wr + 4);
            acc[0] += hv[j] * w0.x; acc[1] += hv[j] * w0.y;
            acc[2] += hv[j] * w0.z; acc[3] += hv[j] * w0.w;
            acc[4] += hv[j] * w1.x; acc[5] += hv[j] * w1.y;
            acc[6] += hv[j] * w1.z; acc[7] += hv[j] * w1.w;
        }
    }
    #pragma unroll
    for (int off = 32; off >= 1; off >>= 1) {
        #pragma unroll
        for (int e = 0; e < 8; e++) acc[e] += __shfl_down(acc[e], off, 64);
    }
    if (lane == 0) {
        float m = acc[0];
        #pragma unroll
        for (int e = 1; e < 8; e++) m = fmaxf(m, acc[e]);
        float ex[8], s = 0.f;
        #pragma unroll
        for (int e = 0; e < 8; e++) { ex[e] = expf(acc[e] - m); s += ex[e]; }
        int best = 0; float bv = -1.f;
        #pragma unroll
        for (int e = 0; e < 8; e++) {
            float p = ex[e] / s;
            if (p > bv) { bv = p; best = e; }
            logits_out[(size_t)token * 8 + e] = acc[e];
        }
        expert_id[token] = best;
        maxprob[token] = bv;
    }
}

// ---------------- capacity scan (proven) ----------------
__global__ __launch_bounds__(64) void scan_k(
    const int* __restrict__ expert_id, int* __restrict__ slot_token,
    int* __restrict__ counts, float* __restrict__ expidx_out)
{
    __shared__ int eids[kS];
    int b = blockIdx.x, tid = threadIdx.x;
    for (int s = tid; s < kS; s += 64) eids[s] = expert_id[b * kS + s];
    __syncthreads();
    if (tid < kE) {
        int e = tid, cnt = 0;
        for (int s = 0; s < kS; s++) {
            if (eids[s] == e) {
                if (cnt < kC) {
                    slot_token[(b * kE + e) * kC + cnt] = s;
                    expidx_out[b * kS + s] = (float)e;
                    cnt++;
                } else {
                    expidx_out[b * kS + s] = 0.f;
                }
            }
        }
        counts[b * kE + e] = cnt;
        for (int c = cnt; c < kC; c++) slot_token[(b * kE + e) * kC + c] = -1;
    }
}

// ---------------- transpose fp32 [R][Cn] -> bf16 [Cn][R]; blockIdx.z = expert ----------------
__global__ void transpose_k(const float* __restrict__ src, u16* __restrict__ dst, int R, int Cn) {
    __shared__ u16 t[32][33];
    size_t eo = (size_t)blockIdx.z * R * Cn;
    int c0 = blockIdx.x * 32, r0 = blockIdx.y * 32;
    int tx = threadIdx.x, ty = threadIdx.y;
    #pragma unroll
    for (int i = 0; i < 4; i++)
        t[ty + i * 8][tx] = f2bf(src[eo + (size_t)(r0 + ty + i * 8) * Cn + c0 + tx]);
    __syncthreads();
    #pragma unroll
    for (int i = 0; i < 4; i++)
        dst[eo + (size_t)(c0 + ty + i * 8) * R + r0 + tx] = t[tx][ty + i * 8];
}

// ---------------- MFMA GEMM1: H = relu(gather(hbf) @ wi), bf16 H ----------------
__global__ __launch_bounds__(256) void gemm1_k(
    const u16* __restrict__ hbf, const u16* __restrict__ wiT, size_t wstride,
    const int* __restrict__ slot_token, const int* __restrict__ counts,
    const u16* __restrict__ zerobuf, u16* __restrict__ Hbuf,
    int pair0, int pstride, int emajor)
{
    int pl = blockIdx.y;
    int pair = emajor ? (((pl & 7) << 3) | (pl >> 3)) : (pair0 + pl * pstride);
    int b = pair >> 3, e = pair & 7;
    const u16* wbase = wiT + (size_t)e * wstride;
    constexpr int NT = kF / 128;  // 32
    int mt = blockIdx.x / NT, nt = blockIdx.x % NT;
    int cnt = counts[pair];
    if (mt * 128 >= cnt) return;

    __shared__ __align__(16) u16 As[128 * 32];
    __shared__ __align__(16) u16 Bs[128 * 32];
    __shared__ int slots[128];
    int tid = threadIdx.x, wave = tid >> 6, lane = tid & 63;
    if (tid < 128) slots[tid] = slot_token[pair * kC + mt * 128 + tid];
    __syncthreads();

    int wr = wave >> 1, wc = wave & 1;
    int fr = lane & 15, fq = lane >> 4;
    int srow = lane >> 2, kb = (lane & 3) * 8;
    // hoisted gather sources for this thread's two A segments
    int sl0 = slots[(wave)     * 16 + srow];
    int sl1 = slots[(wave + 4) * 16 + srow];
    const u16* a0 = (sl0 >= 0) ? hbf + (size_t)(b * kS + sl0) * kD + kb : zerobuf + kb;
    const u16* a1 = (sl1 >= 0) ? hbf + (size_t)(b * kS + sl1) * kD + kb : zerobuf + kb;

    f32x4 acc[4][4];
    #pragma unroll
    for (int m = 0; m < 4; m++)
        #pragma unroll
        for (int n = 0; n < 4; n++) acc[m][n] = (f32x4){0.f, 0.f, 0.f, 0.f};

    for (int k0 = 0; k0 < kD; k0 += 32) {
        gload16(a0 + k0, As + (wave)     * 512);
        gload16(a1 + k0, As + (wave + 4) * 512);
        #pragma unroll
        for (int i = 0; i < 2; i++) {
            int seg = wave + i * 4;
            int row = seg * 16 + srow;
            const u16* srcB = wbase + ((size_t)(nt * 128 + row)) * kD + k0 + kb;
            gload16(srcB, Bs + seg * 512);
        }
        __syncthreads();
        bf16x8 af[4], bfr[4];
        #pragma unroll
        for (int m = 0; m < 4; m++)
            af[m] = *(const bf16x8*)(As + (wr * 64 + m * 16 + fr) * 32 + fq * 8);
        #pragma unroll
        for (int n = 0; n < 4; n++)
            bfr[n] = *(const bf16x8*)(Bs + (wc * 64 + n * 16 + fr) * 32 + fq * 8);
        #pragma unroll
        for (int m = 0; m < 4; m++)
            #pragma unroll
            for (int n = 0; n < 4; n++)
                acc[m][n] = __builtin_amdgcn_mfma_f32_16x16x32_bf16(af[m], bfr[n], acc[m][n], 0, 0, 0);
        __syncthreads();
    }

    size_t hbase = (size_t)pl * kC * kF;
    int r0 = mt * 128 + wr * 64, c0 = nt * 128 + wc * 64;
    #pragma unroll
    for (int m = 0; m < 4; m++) {
        #pragma unroll
        for (int j = 0; j < 4; j++) {
            int row = r0 + m * 16 + fq * 4 + j;
            size_t rb = hbase + (size_t)row * kF;
            #pragma unroll
            for (int n = 0; n < 4; n++) {
                int col = c0 + n * 16 + fr;
                Hbuf[rb + col] = f2bf(fmaxf(acc[m][n][j], 0.f));
            }
        }
    }
}

// ---------------- MFMA GEMM2: out = (H @ wo) * max_prob, fp32 scatter ----------------
__global__ __launch_bounds__(256) void gemm2_k(
    const u16* __restrict__ Hbuf, const u16* __restrict__ woT, size_t wstride,
    const int* __restrict__ slot_token, const int* __restrict__ counts,
    const float* __restrict__ maxprob, float* __restrict__ outp,
    int pair0, int pstride, int emajor)
{
    int pl = blockIdx.y;
    int pair = emajor ? (((pl & 7) << 3) | (pl >> 3)) : (pair0 + pl * pstride);
    int b = pair >> 3, e = pair & 7;
    const u16* wbase = woT + (size_t)e * wstride;
    constexpr int NT = kD / 128;  // 8
    int mt = blockIdx.x / NT, nt = blockIdx.x % NT;
    int cnt = counts[pair];
    if (mt * 128 >= cnt) return;

    __shared__ __align__(16) u16 As[128 * 32];
    __shared__ __align__(16) u16 Bs[128 * 32];
    __shared__ int slots[128];
    int tid = threadIdx.x, wave = tid >> 6, lane = tid & 63;
    if (tid < 128) slots[tid] = slot_token[pair * kC + mt * 128 + tid];
    __syncthreads();

    int wr = wave >> 1, wc = wave & 1;
    int fr = lane & 15, fq = lane >> 4;
    int srow = lane >> 2, kb = (lane & 3) * 8;
    f32x4 acc[4][4];
    #pragma unroll
    for (int m = 0; m < 4; m++)
        #pragma unroll
        for (int n = 0; n < 4; n++) acc[m][n] = (f32x4){0.f, 0.f, 0.f, 0.f};

    for (int k0 = 0; k0 < kF; k0 += 32) {
        #pragma unroll
        for (int i = 0; i < 2; i++) {
            int seg = wave + i * 4;
            int row = seg * 16 + srow;
            const u16* srcA = Hbuf + ((size_t)pl * kC + mt * 128 + row) * kF + k0 + kb;
            gload16(srcA, As + seg * 512);
            const u16* srcB = wbase + ((size_t)(nt * 128 + row)) * kF + k0 + kb;
            gload16(srcB, Bs + seg * 512);
        }
        __syncthreads();
        bf16x8 af[4], bfr[4];
        #pragma unroll
        for (int m = 0; m < 4; m++)
            af[m] = *(const bf16x8*)(As + (wr * 64 + m * 16 + fr) * 32 + fq * 8);
        #pragma unroll
        for (int n = 0; n < 4; n++)
            bfr[n] = *(const bf16x8*)(Bs + (wc * 64 + n * 16 + fr) * 32 + fq * 8);
        #pragma unroll
        for (int m = 0; m < 4; m++)
            #pragma unroll
            for (int n = 0; n < 4; n++)
                acc[m][n] = __builtin_amdgcn_mfma_f32_16x16x32_bf16(af[m], bfr[n], acc[m][n], 0, 0, 0);
        __syncthreads();
    }

    int c0 = nt * 128 + wc * 64;
    #pragma unroll
    for (int m = 0; m < 4; m++) {
        #pragma unroll
        for (int j = 0; j < 4; j++) {
            int rlocal = wr * 64 + m * 16 + fq * 4 + j;
            int s = slots[rlocal];
            if (s >= 0) {
                float p = maxprob[b * kS + s];
                size_t ob = (size_t)(b * kS + s) * kD;
                #pragma unroll
                for (int n = 0; n < 4; n++) {
                    int col = c0 + n * 16 + fr;
                    outp[ob + col] = acc[m][n][j] * p;
                }
            }
        }
    }
}

// ---------------- naive fp32 fallback (proven) ----------------
__global__ __launch_bounds__(256) void ngemm1_k(
    const float* __restrict__ hidden, const float* __restrict__ wi,
    const int* __restrict__ slot_token, const int* __restrict__ counts,
    float* __restrict__ H, int pair)
{
    int b = pair >> 3, e = pair & 7;
    int cnt = counts[pair];
    int c0 = blockIdx.y * 64, f0 = blockIdx.x * 64;
    if (c0 >= cnt) return;
    __shared__ float As[64][17];
    __shared__ float Bs[16][65];
    __shared__ int slots[64];
    int tx = threadIdx.x, ty = threadIdx.y;
    int tid = ty * 16 + tx;
    if (tid < 64) slots[tid] = slot_token[pair * kC + c0 + tid];
    __syncthreads();
    float acc[4][4];
    #pragma unroll
    for (int i = 0; i < 4; i++)
        #pragma unroll
        for (int j = 0; j < 4; j++) acc[i][j] = 0.f;
    int ar = tid >> 2, ak = (tid & 3) * 4;
    int bd = tid >> 4, bf = (tid & 15) * 4;
    const float* wie = wi + (size_t)e * kD * kF;
    for (int k0 = 0; k0 < kD; k0 += 16) {
        int sl = slots[ar];
        if (sl >= 0) {
            float4 v = *(const float4*)(hidden + (size_t)(b * kS + sl) * kD + k0 + ak);
            As[ar][ak] = v.x; As[ar][ak + 1] = v.y; As[ar][ak + 2] = v.z; As[ar][ak + 3] = v.w;
        } else {
            As[ar][ak] = 0.f; As[ar][ak + 1] = 0.f; As[ar][ak + 2] = 0.f; As[ar][ak + 3] = 0.f;
        }
        float4 w = *(const float4*)(wie + (size_t)(k0 + bd) * kF + f0 + bf);
        Bs[bd][bf] = w.x; Bs[bd][bf + 1] = w.y; Bs[bd][bf + 2] = w.z; Bs[bd][bf + 3] = w.w;
        __syncthreads();
        #pragma unroll
        for (int kk = 0; kk < 16; kk++) {
            float a[4], bv[4];
            #pragma unroll
            for (int i = 0; i < 4; i++) a[i] = As[ty * 4 + i][kk];
            #pragma unroll
            for (int j = 0; j < 4; j++) bv[j] = Bs[kk][tx * 4 + j];
            #pragma unroll
            for (int i = 0; i < 4; i++)
                #pragma unroll
                for (int j = 0; j < 4; j++) acc[i][j] += a[i] * bv[j];
        }
        __syncthreads();
    }
    #pragma unroll
    for (int i = 0; i < 4; i++) {
        int row = c0 + ty * 4 + i;
        #pragma unroll
        for (int j = 0; j < 4; j++)
            H[(size_t)row * kF + f0 + tx * 4 + j] = fmaxf(acc[i][j], 0.f);
    }
}

__global__ __launch_bounds__(256) void ngemm2_k(
    const float* __restrict__ H, const float* __restrict__ wo,
    const int* __restrict__ slot_token, const int* __restrict__ counts,
    const float* __restrict__ maxprob, float* __restrict__ outp, int pair)
{
    int b = pair >> 3, e = pair & 7;
    int cnt = counts[pair];
    int c0 = blockIdx.y * 64, d0 = blockIdx.x * 64;
    if (c0 >= cnt) return;
    __shared__ float As[64][17];
    __shared__ float Bs[16][65];
    __shared__ int slots[64];
    int tx = threadIdx.x, ty = threadIdx.y;
    int tid = ty * 16 + tx;
    if (tid < 64) slots[tid] = slot_token[pair * kC + c0 + tid];
    __syncthreads();
    float acc[4][4];
    #pragma unroll
    for (int i = 0; i < 4; i++)
        #pragma unroll
        for (int j = 0; j < 4; j++) acc[i][j] = 0.f;
    int ar = tid >> 2, ak = (tid & 3) * 4;
    int bd = tid >> 4, bf = (tid & 15) * 4;
    const float* woe = wo + (size_t)e * kF * kD;
    for (int k0 = 0; k0 < kF; k0 += 16) {
        float4 v = *(const float4*)(H + (size_t)(c0 + ar) * kF + k0 + ak);
        As[ar][ak] = v.x; As[ar][ak + 1] = v.y; As[ar][ak + 2] = v.z; As[ar][ak + 3] = v.w;
        float4 w = *(const float4*)(woe + (size_t)(k0 + bd) * kD + d0 + bf);
        Bs[bd][bf] = w.x; Bs[bd][bf + 1] = w.y; Bs[bd][bf + 2] = w.z; Bs[bd][bf + 3] = w.w;
        __syncthreads();
        #pragma unroll
        for (int kk = 0; kk < 16; kk++) {
            float a[4], bv[4];
            #pragma unroll
            for (int i = 0; i < 4; i++) a[i] = As[ty * 4 + i][kk];
            #pragma unroll
            for (int j = 0; j < 4; j++) bv[j] = Bs[kk][tx * 4 + j];
            #pragma unroll
            for (int i = 0; i < 4; i++)
                #pragma unroll
                for (int j = 0; j < 4; j++) acc[i][j] += a[i] * bv[j];
        }
        __syncthreads();
    }
    #pragma unroll
    for (int i = 0; i < 4; i++) {
        int s = slots[ty * 4 + i];
        if (s >= 0) {
            float p = maxprob[b * kS + s];
            size_t ob = (size_t)(b * kS + s) * kD;
            #pragma unroll
            for (int j = 0; j < 4; j++)
                outp[ob + d0 + tx * 4 + j] = acc[i][j] * p;
        }
    }
}

extern "C" void kernel_launch(void* const* d_in, const int* in_sizes, int n_in,
                              void* d_out, int out_size, void* d_ws, size_t ws_size,
                              hipStream_t stream)
{
    const float* hidden = (const float*)d_in[0];
    const float* rw     = (const float*)d_in[1];
    const float* wi     = (const float*)d_in[2];
    const float* wo     = (const float*)d_in[3];
    float* outp   = (float*)d_out;
    float* logits = outp + (size_t)kB * kS * kD;
    float* expidx = logits + (size_t)kB * kS * kE;

    char* ws = (char*)d_ws;
    size_t off = 0;
    auto alloc = [&](size_t bytes) -> char* {
        char* p = ws + off; off += (bytes + 255) & ~(size_t)255; return p;
    };
    int*   slot_token = (int*)  alloc((size_t)kB * kE * kC * 4);
    int*   counts     = (int*)  alloc((size_t)kB * kE * 4);
    int*   expert_id  = (int*)  alloc((size_t)kB * kS * 4);
    float* maxprob    = (float*)alloc((size_t)kB * kS * 4);
    size_t small_off = off;               // ~1.2 MiB

    const size_t wsz    = (size_t)kD * kF * 2;       // 8 MiB per expert, bf16
    const size_t hsz    = (size_t)kC * kF * 2;       // 4 MiB per pair, bf16
    const size_t hbfsz  = (size_t)kB * kS * kD * 2;  // 32 MiB bf16 hidden image

    init_k<<<2048, 256, 0, stream>>>((uint4*)outp);
    router_k<<<kB * kS / 4, 256, 0, stream>>>(hidden, rw, logits, expert_id, maxprob);
    scan_k<<<kB, 64, 0, stream>>>(expert_id, slot_token, counts, expidx);

    if (ws_size >= small_off + 2 * kE * wsz + hbfsz + 4096 + 4 * hsz) {
        // ---- tier A: all-expert transposed weights + bf16 hidden image ----
        u16* wiT = (u16*)alloc(kE * wsz);   // 64 MiB
        u16* woT = (u16*)alloc(kE * wsz);   // 64 MiB
        u16* hbf = (u16*)alloc(hbfsz);      // 32 MiB
        u16* zerobuf = (u16*)alloc(4096);
        int Gb = (int)((ws_size - off) / hsz);
        if (Gb > kB * kE) Gb = kB * kE;
        u16* Hbuf = (u16*)alloc((size_t)Gb * hsz);
        conv_hidden_k<<<2048, 256, 0, stream>>>(hidden, hbf, (uint4*)zerobuf);
        transpose_k<<<dim3(kF / 32, kD / 32, kE), dim3(32, 8), 0, stream>>>(wi, wiT, kD, kF);
        transpose_k<<<dim3(kD / 32, kF / 32, kE), dim3(32, 8), 0, stream>>>(wo, woT, kF, kD);
        for (int p0 = 0; p0 < kB * kE; p0 += Gb) {
            int g = kB * kE - p0 < Gb ? kB * kE - p0 : Gb;
            int emajor = (g == kB * kE) ? 1 : 0;   // expert-major y-order for weight L3 locality
            gemm1_k<<<dim3((kC / 128) * (kF / 128), g), 256, 0, stream>>>(
                hbf, wiT, (size_t)kD * kF, slot_token, counts, zerobuf, Hbuf, p0, 1, emajor);
            gemm2_k<<<dim3((kC / 128) * (kD / 128), g), 256, 0, stream>>>(
                Hbuf, woT, (size_t)kD * kF, slot_token, counts, maxprob, outp, p0, 1, emajor);
        }
    } else if (ws_size >= small_off + 2 * wsz + hbfsz + 4096 + hsz) {
        // ---- tier B: per-expert transposed weights ----
        u16* wiT = (u16*)alloc(wsz);
        u16* woT = (u16*)alloc(wsz);
        u16* hbf = (u16*)alloc(hbfsz);
        u16* zerobuf = (u16*)alloc(4096);
        int Gb = (int)((ws_size - off) / hsz);
        if (Gb > kB) Gb = kB;
        u16* Hbuf = (u16*)alloc((size_t)Gb * hsz);
        conv_hidden_k<<<2048, 256, 0, stream>>>(hidden, hbf, (uint4*)zerobuf);
        for (int e = 0; e < kE; e++) {
            transpose_k<<<dim3(kF / 32, kD / 32, 1), dim3(32, 8), 0, stream>>>(
                wi + (size_t)e * kD * kF, wiT, kD, kF);
            transpose_k<<<dim3(kD / 32, kF / 32, 1), dim3(32, 8), 0, stream>>>(
                wo + (size_t)e * kD * kF, woT, kF, kD);
            for (int b0 = 0; b0 < kB; b0 += Gb) {
                int g = kB - b0 < Gb ? kB - b0 : Gb;
                gemm1_k<<<dim3((kC / 128) * (kF / 128), g), 256, 0, stream>>>(
                    hbf, wiT, 0, slot_token, counts, zerobuf, Hbuf, b0 * kE + e, kE, 0);
                gemm2_k<<<dim3((kC / 128) * (kD / 128), g), 256, 0, stream>>>(
                    Hbuf, woT, 0, slot_token, counts, maxprob, outp, b0 * kE + e, kE, 0);
            }
        }
    } else {
        // ---- tier C: proven naive fp32 fallback ----
        float* H = (float*)alloc((size_t)kC * kF * 4);
        for (int pair = 0; pair < kB * kE; pair++) {
            ngemm1_k<<<dim3(kF / 64, kC / 64), dim3(16, 16), 0, stream>>>(
                hidden, wi, slot_token, counts, H, pair);
            ngemm2_k<<<dim3(kD / 64, kC / 64), dim3(16, 16), 0, stream>>>(
                H, wo, slot_token, counts, maxprob, outp, pair);
        }
    }
}